// Round 9
// baseline (405.539 us; speedup 1.0000x reference)
//
#include <hip/hip_runtime.h>
#include <math.h>

#define IMG_W 3840
#define IMG_H 2160
#define OUTW  120       // output cols per wave (32 strips: 32*120 = 3840 exact)
#define R     10        // output rows per strip (2160 = 216 * 10)
#define ITERS (R + 4)   // 14 gray rows per strip
#define CAP   128       // per-wave defer-list capacity (expect ~1)

// idx -> dx [1,1,0,-1,-1,-1,0,1], dy [0,1,1,1,0,-1,-1,-1], packed as (d+1) 2-bit fields
#define DXPACK 0x901A
#define DYPACK 0x1A9
// Sector boundary slopes in scaled-degree space (RAD2DEG = 180/3.14159)
#define T1_SLOPE 0.41421317376456f
#define T2_SLOPE 2.41420676743300f
#define SECT_EPS  3.0e-5f
#define QE        0.04f      // 0.2^2 threshold on squared magnitude
#define QBAND_EPS 1.0e-4f
#define TIE_EPS   1.0e-4f

// ---------- exact reference numerics (cold path only) ----------
__device__ __forceinline__ int slow_sector(float sx, float sy) {
#pragma clang fp contract(off)
    const float RADF = (float)(180.0 / 3.14159);
    float t = atan2f(sy, sx);
    float wvv = ((t * RADF) + 180.0f) / 45.0f;  // exact f32 chain as reference
    float ori = rintf(wvv);                     // round-half-even == np.round
    float fr = fabsf(wvv - ori);
    if (fr > 0.4995f) {
        double td = atan2((double)sy, (double)sx);
        float t2 = (float)td;
        wvv = ((t2 * RADF) + 180.0f) / 45.0f;
        ori = rintf(wvv);
    }
    return ((int)ori) & 7;
}

__device__ __forceinline__ float gray_at(const float* img, int xx, int yy) {
#pragma clang fp contract(off)
    if ((unsigned)xx >= (unsigned)IMG_W || (unsigned)yy >= (unsigned)IMG_H) return 0.0f;
    size_t o = (size_t)yy * IMG_W + xx;
    float c0 = img[o];
    float c1 = img[o + (size_t)IMG_W * IMG_H];
    float c2 = img[o + 2 * (size_t)IMG_W * IMG_H];
    return ((c0 + c1) + c2) / 3.0f;             // exact reference gray
}

__device__ void sobel_at(const float* img, int xx, int yy, float& sxo, float& syo) {
#pragma clang fp contract(off)
    float a00 = gray_at(img, xx - 1, yy - 1), a01 = gray_at(img, xx, yy - 1), a02 = gray_at(img, xx + 1, yy - 1);
    float a10 = gray_at(img, xx - 1, yy),                                     a12 = gray_at(img, xx + 1, yy);
    float a20 = gray_at(img, xx - 1, yy + 1), a21 = gray_at(img, xx, yy + 1), a22 = gray_at(img, xx + 1, yy + 1);
    float s = a00;
    s = s - a02;
    s = s + 2.0f * a10;
    s = s - 2.0f * a12;
    s = s + a20;
    s = s - a22;
    sxo = s;
    float t = a00;
    t = t + 2.0f * a01;
    t = t + a02;
    t = t - a20;
    t = t - 2.0f * a21;
    t = t - a22;
    syo = t;
}

__device__ float mag_at(const float* img, int xx, int yy) {
#pragma clang fp contract(off)
    if ((unsigned)xx >= (unsigned)IMG_W || (unsigned)yy >= (unsigned)IMG_H) return 0.0f;
    float sx, sy;
    sobel_at(img, xx, yy, sx, sy);
    return sqrtf(sx * sx + sy * sy);
}

// ---------- main kernel: array-free scalar pipeline, div/sqrt-free fast path ----------
__global__ __launch_bounds__(256) void canny_main(const float* __restrict__ img,
                                                  float* __restrict__ out) {
    __shared__ float ring[4][4][128];           // per-wave 4-row ring of squared mags (8 KB)
    __shared__ unsigned fixl[4][CAP];           // deferred pixels (2 KB)
    __shared__ unsigned fixn[4];

    const int lane = threadIdx.x;               // 0..63
    const int wv   = threadIdx.y;               // 0..3
    if (lane == 0) fixn[wv] = 0u;               // wave-private; same-wave DS in-order
    float* sb = &ring[wv][0][0];
    unsigned* flist = fixl[wv];

    const int X0 = (blockIdx.x * 4 + wv) * OUTW;
    const int Y0 = blockIdx.y * R;
    const int r0 = 2 * lane;                    // rel cols r0, r0+1 (image X0-2+r0)
    const int x0i = X0 - 2 + r0;
    const int x1i = x0i + 1;
    const bool xk0 = (unsigned)x0i < (unsigned)IMG_W;
    const bool xk1 = (unsigned)x1i < (unsigned)IMG_W;
    const bool outok = (lane >= 1) && (lane <= 60);  // out cols X0..X0+119
    const int rb = outok ? r0 : 2;              // safe LDS read index for masked lanes
    const int xc = min(max(x0i, 0), IMG_W - 2); // even -> aligned float2

    const float* p0 = img + xc;
    const float* p1 = p0 + (size_t)IMG_W * IMG_H;
    const float* p2 = p1 + (size_t)IMG_W * IMG_H;
    const float INV3 = 1.0f / 3.0f;

    // depth-2 raw prefetch, all named scalars (no arrays -> no scratch risk)
    float2 A0, B0, C0, A1, B1, C1;
    {
        int yc = min(max(Y0 - 2, 0), IMG_H - 1);
        size_t o = (size_t)yc * IMG_W;
        A0 = *(const float2*)(p0 + o); B0 = *(const float2*)(p1 + o); C0 = *(const float2*)(p2 + o);
        yc = min(max(Y0 - 1, 0), IMG_H - 1);
        o = (size_t)yc * IMG_W;
        A1 = *(const float2*)(p0 + o); B1 = *(const float2*)(p1 + o); C1 = *(const float2*)(p2 + o);
    }

    // rolling derived rows (A=row k-2, B=k-1, C=k), named scalars
    float dhA = 0, dhB = 0, dhC = 0;            // gl - g1   (-> sx of px0)
    float dvA = 0, dvB = 0, dvC = 0;            // g0 - gr   (-> sx of px1)
    float tsA = 0, tsB = 0, tsC = 0;            // gl + 2*g0 + g1 (-> sy of px0)
    float tvA = 0, tvB = 0, tvC = 0;            // g0 + 2*g1 + gr (-> sy of px1)
    // lag-1 state (mag row produced previous iteration)
    float mq0 = 0.f, mq1 = 0.f;
    int offP0 = 512, offN0 = 512, offP1 = 512, offN1 = 512;
    bool unc0 = false, unc1 = false;
    int sW = 0;                                 // ring write offset (elements)

    for (int k = 0; k < ITERS; ++k) {
        const int y = Y0 - 2 + k;
        // ---- prefetch raw row k+2 (unconditional clamped) ----
        float2 An, Bn, Cn;
        {
            int kk = (k + 2 < ITERS) ? (k + 2) : (ITERS - 1);
            int yc2 = min(max(Y0 - 2 + kk, 0), IMG_H - 1);
            size_t o2 = (size_t)yc2 * IMG_W;
            An = *(const float2*)(p0 + o2);
            Bn = *(const float2*)(p1 + o2);
            Cn = *(const float2*)(p2 + o2);
        }
        // ---- gray of row k (masked); fast *INV3, exactness via defer bands ----
        const bool yok = (unsigned)y < (unsigned)IMG_H;
        float g0 = (yok && xk0) ? ((A0.x + B0.x) + C0.x) * INV3 : 0.0f;
        float g1 = (yok && xk1) ? ((A0.y + B0.y) + C0.y) * INV3 : 0.0f;
        float gl = __shfl_up(g1, 1);            // col r0-1
        float gr = __shfl_down(g0, 1);          // col r0+2
        // rotate derived, append row k
        dhA = dhB; dhB = dhC; dhC = gl - g1;
        dvA = dvB; dvB = dvC; dvC = g0 - gr;
        tsA = tsB; tsB = tsC; tsC = fmaf(2.0f, g0, gl + g1);
        tvA = tvB; tvB = tvC; tvC = fmaf(2.0f, g1, g0 + gr);
        // rotate raw
        A0 = A1; B0 = B1; C0 = C1; A1 = An; B1 = Bn; C1 = Cn;

        if (k >= 2) {
            const int m = Y0 + k - 3;           // mag row being produced
            const bool mok = (unsigned)m < (unsigned)IMG_H;
            float sx0 = fmaf(2.0f, dhB, dhA + dhC);
            float sy0 = tsA - tsC;
            float sx1 = fmaf(2.0f, dvB, dvA + dvC);
            float sy1 = tvA - tvC;
            float q0 = fmaf(sx0, sx0, sy0 * sy0);   // squared magnitude
            float q1 = fmaf(sx1, sx1, sy1 * sy1);
            float Q0 = (mok && xk0) ? q0 : 0.0f;    // grad_mag zero-padded outside HxW
            float Q1 = (mok && xk1) ? q1 : 0.0f;

            // sector from slope signs; knife-edge cases flagged for exact fixup
            float ax0 = fabsf(sx0), ay0 = fabsf(sy0);
            float d10 = fmaf(-T1_SLOPE, ax0, ay0);
            float d20 = fmaf(-T2_SLOPE, ax0, ay0);
            float e0 = SECT_EPS * (ax0 + ay0);
            int ndx0 = (d20 > 0.0f) ? 0 : ((sx0 > 0.0f) ? -1 : 1);
            int ndy0 = (d10 < 0.0f) ? 0 : ((sy0 > 0.0f) ? -1 : 1);
            bool nu0 = (fminf(fabsf(d10), fabsf(d20)) < e0)
                     || (fabsf(q0 - QE) <= QBAND_EPS * (q0 + QE));

            float ax1 = fabsf(sx1), ay1 = fabsf(sy1);
            float d11 = fmaf(-T1_SLOPE, ax1, ay1);
            float d21 = fmaf(-T2_SLOPE, ax1, ay1);
            float e1 = SECT_EPS * (ax1 + ay1);
            int ndx1 = (d21 > 0.0f) ? 0 : ((sx1 > 0.0f) ? -1 : 1);
            int ndy1 = (d11 < 0.0f) ? 0 : ((sy1 > 0.0f) ? -1 : 1);
            bool nu1 = (fminf(fabsf(d11), fabsf(d21)) < e1)
                     || (fabsf(q1 - QE) <= QBAND_EPS * (q1 + QE));

            // ring write: row m -> slot sW; same-wave DS in-order -> no barrier
            *(float2*)(sb + sW + r0) = make_float2(Q0, Q1);

            // ---- NMS for row n = m-1 (rows m-2,m-1,m at sW-256,sW-128,sW mod 512) ----
            if (k >= 4) {
                const int n = m - 1;            // = Y0 + k - 4
                const int cen0 = ((sW + 384) & 511) + rb;   // row n, col rb
                float mp0 = sb[(cen0 + offP0) & 511];
                float mn0 = sb[(cen0 + offN0) & 511];
                float mp1 = sb[(cen0 + 1 + offP1) & 511];
                float mn1 = sb[(cen0 + 1 + offN1) & 511];
                float r0v = (mq0 > mp0 && mq0 > mn0 && mq0 >= QE) ? 1.0f : 0.0f;
                float r1v = (mq1 > mp1 && mq1 > mn1 && mq1 >= QE) ? 1.0f : 0.0f;
                if (outok)
                    *(float2*)(out + (size_t)n * IMG_W + x0i) = make_float2(r0v, r1v);
                // defer knife-edge pixels to the exact path
                float tb0 = TIE_EPS * mq0, tb1 = TIE_EPS * mq1;
                bool tie0 = (fabsf(mq0 - mp0) <= tb0) || (fabsf(mq0 - mn0) <= tb0);
                bool tie1 = (fabsf(mq1 - mp1) <= tb1) || (fabsf(mq1 - mn1) <= tb1);
                bool cand0 = mq0 >= QE * (1.0f - 3.0f * QBAND_EPS);
                bool cand1 = mq1 >= QE * (1.0f - 3.0f * QBAND_EPS);
                bool f0 = outok && cand0 && (unc0 || tie0);
                bool f1 = outok && cand1 && (unc1 || tie1);
                if (f0) {
                    unsigned id = atomicAdd(&fixn[wv], 1u);
                    if (id < CAP) flist[id] = ((unsigned)n << 12) | (unsigned)x0i;
                }
                if (f1) {
                    unsigned id = atomicAdd(&fixn[wv], 1u);
                    if (id < CAP) flist[id] = ((unsigned)n << 12) | (unsigned)x1i;
                }
            }
            // lag update
            mq0 = Q0; mq1 = Q1;
            int o0 = ndy0 * 128 + ndx0, o1 = ndy1 * 128 + ndx1;
            offP0 = o0 + 512; offN0 = 512 - o0;
            offP1 = o1 + 512; offN1 = 512 - o1;
            unc0 = nu0; unc1 = nu1;
            sW = (sW + 128) & 511;
        }
    }

    // ---- in-wave fixup: exact reference numerics for deferred pixels ----
    __threadfence();                            // retire fast-path stores before overwrite
    unsigned nf = fixn[wv];
    if (nf > CAP) nf = CAP;
    for (unsigned i = lane; i < nf; i += 64) {
        unsigned pk = flist[i];
        int xx = (int)(pk & 4095u), yy = (int)(pk >> 12);
        float sx, sy;
        sobel_at(img, xx, yy, sx, sy);          // exact gray (/3.0f) + exact taps
        int idx = slow_sector(sx, sy);          // exact atan2 (+double rescue)
        int dxo = ((DXPACK >> (2 * idx)) & 3) - 1;
        int dyo = ((DYPACK >> (2 * idx)) & 3) - 1;
        float mc = mag_at(img, xx, yy);
        float mp = mag_at(img, xx + dxo, yy + dyo);
        float mn = mag_at(img, xx - dxo, yy - dyo);
        out[(size_t)yy * IMG_W + xx] =
            (fminf(mc - mp, mc - mn) > 0.0f && mc >= 0.2f) ? 1.0f : 0.0f;
    }
}

extern "C" void kernel_launch(void* const* d_in, const int* in_sizes, int n_in,
                              void* d_out, int out_size, void* d_ws, size_t ws_size,
                              hipStream_t stream) {
    const float* img = (const float*)d_in[0];
    float* out = (float*)d_out;
    canny_main<<<dim3(8, IMG_H / R), dim3(64, 4), 0, stream>>>(img, out);
}

// Round 10
// 373.193 us; speedup vs baseline: 1.0867x; 1.0867x over previous
//
#include <hip/hip_runtime.h>
#include <math.h>

#define IMG_W 3840
#define IMG_H 2160
#define OUTW  120       // output cols per wave (32 strips: 32*120 = 3840 exact)
#define R     12        // output rows per strip (2160 = 180 * 12)
#define ITERS (R + 4)   // 16 gray rows per strip
#define CAP   64        // per-wave defer-list capacity (expect ~0.2 used)

// idx -> dx [1,1,0,-1,-1,-1,0,1], dy [0,1,1,1,0,-1,-1,-1], packed as (d+1) 2-bit fields
#define DXPACK 0x901A
#define DYPACK 0x1A9
// Sector boundary slopes in scaled-degree space (RAD2DEG = 180/3.14159)
#define T1_SLOPE 0.41421317376456f
#define T2_SLOPE 2.41420676743300f
#define SECT_EPS  3.0e-5f
#define QE        0.04f      // 0.2^2 threshold on squared magnitude
#define QBAND_EPS 1.0e-4f
#define TIE_EPS   1.0e-4f

// ---------- exact reference numerics (cold path only) ----------
__device__ __forceinline__ int slow_sector(float sx, float sy) {
#pragma clang fp contract(off)
    const float RADF = (float)(180.0 / 3.14159);
    float t = atan2f(sy, sx);
    float wvv = ((t * RADF) + 180.0f) / 45.0f;  // exact f32 chain as reference
    float ori = rintf(wvv);                     // round-half-even == np.round
    float fr = fabsf(wvv - ori);
    if (fr > 0.4995f) {
        double td = atan2((double)sy, (double)sx);
        float t2 = (float)td;
        wvv = ((t2 * RADF) + 180.0f) / 45.0f;
        ori = rintf(wvv);
    }
    return ((int)ori) & 7;
}

__device__ __forceinline__ float gray_at(const float* img, int xx, int yy) {
#pragma clang fp contract(off)
    if ((unsigned)xx >= (unsigned)IMG_W || (unsigned)yy >= (unsigned)IMG_H) return 0.0f;
    size_t o = (size_t)yy * IMG_W + xx;
    float c0 = img[o];
    float c1 = img[o + (size_t)IMG_W * IMG_H];
    float c2 = img[o + 2 * (size_t)IMG_W * IMG_H];
    return ((c0 + c1) + c2) / 3.0f;             // exact reference gray
}

__device__ void sobel_at(const float* img, int xx, int yy, float& sxo, float& syo) {
#pragma clang fp contract(off)
    float a00 = gray_at(img, xx - 1, yy - 1), a01 = gray_at(img, xx, yy - 1), a02 = gray_at(img, xx + 1, yy - 1);
    float a10 = gray_at(img, xx - 1, yy),                                     a12 = gray_at(img, xx + 1, yy);
    float a20 = gray_at(img, xx - 1, yy + 1), a21 = gray_at(img, xx, yy + 1), a22 = gray_at(img, xx + 1, yy + 1);
    float s = a00;
    s = s - a02;
    s = s + 2.0f * a10;
    s = s - 2.0f * a12;
    s = s + a20;
    s = s - a22;
    sxo = s;
    float t = a00;
    t = t + 2.0f * a01;
    t = t + a02;
    t = t - a20;
    t = t - 2.0f * a21;
    t = t - a22;
    syo = t;
}

__device__ float mag_at(const float* img, int xx, int yy) {
#pragma clang fp contract(off)
    if ((unsigned)xx >= (unsigned)IMG_W || (unsigned)yy >= (unsigned)IMG_H) return 0.0f;
    float sx, sy;
    sobel_at(img, xx, yy, sx, sy);
    return sqrtf(sx * sx + sy * sy);
}

// ---------- main kernel: R6 structure (full unroll, lean body) x R8 numerics ----------
__global__ __launch_bounds__(256, 2) void canny_main(const float* __restrict__ img,
                                                     float* __restrict__ out) {
    __shared__ float ring[4][4][128];           // per-wave 4-row ring of squared mags (8 KB)
    __shared__ unsigned fixl[4][CAP];           // deferred pixels (1 KB)
    __shared__ unsigned fixn[4];

    const int lane = threadIdx.x;               // 0..63
    const int wv   = threadIdx.y;               // 0..3
    if (lane == 0) fixn[wv] = 0u;               // wave-private; same-wave DS in-order
    float* sb = &ring[wv][0][0];
    unsigned* flist = fixl[wv];

    const int X0 = (blockIdx.x * 4 + wv) * OUTW;
    const int Y0 = blockIdx.y * R;
    const int r0 = 2 * lane;                    // rel cols r0, r0+1 (image X0-2+r0)
    const int x0i = X0 - 2 + r0;
    const int x1i = x0i + 1;
    const bool xk0 = (unsigned)x0i < (unsigned)IMG_W;
    const bool xk1 = (unsigned)x1i < (unsigned)IMG_W;
    const bool outok = (lane >= 1) && (lane <= 60);  // out cols X0..X0+119
    const int rb = outok ? r0 : 2;              // safe LDS read index for masked lanes
    const int xc = min(max(x0i, 0), IMG_W - 2); // even -> aligned float2

    const float* p0 = img + xc;
    const float* p1 = p0 + (size_t)IMG_W * IMG_H;
    const float* p2 = p1 + (size_t)IMG_W * IMG_H;
    const float INV3 = 1.0f / 3.0f;

    // rolling derived rows (A=row k-2, B=k-1, C=k) — named scalars; the rotation
    // becomes register renaming under full unroll (no arrays -> no scratch)
    float dhA = 0, dhB = 0, dhC = 0;            // gl - g1   (-> sx of px0)
    float dvA = 0, dvB = 0, dvC = 0;            // g0 - gr   (-> sx of px1)
    float tsA = 0, tsB = 0, tsC = 0;            // gl + 2*g0 + g1 (-> sy of px0)
    float tvA = 0, tvB = 0, tvC = 0;            // g0 + 2*g1 + gr (-> sy of px1)
    // lag-1 state (mag row produced previous iteration)
    float mq0 = 0.f, mq1 = 0.f;
    int offP0 = 512, offN0 = 512, offP1 = 512, offN1 = 512;
    bool unc0 = false, unc1 = false;

#pragma unroll
    for (int k = 0; k < ITERS; ++k) {
        const int y = Y0 - 2 + k;
        const bool yok = (unsigned)y < (unsigned)IMG_H;
        // unconditional clamped load of row k (scheduler hoists these freely)
        const int yc = min(max(y, 0), IMG_H - 1);
        const size_t o = (size_t)yc * IMG_W;
        const float2 A = *(const float2*)(p0 + o);
        const float2 B = *(const float2*)(p1 + o);
        const float2 C = *(const float2*)(p2 + o);
        // approx gray (*INV3); exactness recovered via defer bands + fixup
        float g0 = (yok && xk0) ? ((A.x + B.x) + C.x) * INV3 : 0.0f;
        float g1 = (yok && xk1) ? ((A.y + B.y) + C.y) * INV3 : 0.0f;
        float gl = __shfl_up(g1, 1);            // col r0-1
        float gr = __shfl_down(g0, 1);          // col r0+2
        dhA = dhB; dhB = dhC; dhC = gl - g1;
        dvA = dvB; dvB = dvC; dvC = g0 - gr;
        tsA = tsB; tsB = tsC; tsC = fmaf(2.0f, g0, gl + g1);
        tvA = tvB; tvB = tvC; tvC = fmaf(2.0f, g1, g0 + gr);

        if (k >= 2) {                           // folds at compile time under unroll
            const int m = Y0 + k - 3;           // mag row being produced
            const bool mok = (unsigned)m < (unsigned)IMG_H;
            float sx0 = fmaf(2.0f, dhB, dhA + dhC);
            float sy0 = tsA - tsC;
            float sx1 = fmaf(2.0f, dvB, dvA + dvC);
            float sy1 = tvA - tvC;
            float q0 = fmaf(sx0, sx0, sy0 * sy0);   // squared magnitude
            float q1 = fmaf(sx1, sx1, sy1 * sy1);
            float Q0 = (mok && xk0) ? q0 : 0.0f;    // grad_mag zero-padded outside HxW
            float Q1 = (mok && xk1) ? q1 : 0.0f;

            // sector from slope signs; knife-edge cases flagged for exact fixup
            float ax0 = fabsf(sx0), ay0 = fabsf(sy0);
            float d10 = fmaf(-T1_SLOPE, ax0, ay0);
            float d20 = fmaf(-T2_SLOPE, ax0, ay0);
            float e0 = SECT_EPS * (ax0 + ay0);
            int ndx0 = (d20 > 0.0f) ? 0 : ((sx0 > 0.0f) ? -1 : 1);
            int ndy0 = (d10 < 0.0f) ? 0 : ((sy0 > 0.0f) ? -1 : 1);
            bool nu0 = (fminf(fabsf(d10), fabsf(d20)) < e0)
                     || (fabsf(q0 - QE) <= QBAND_EPS * (q0 + QE));

            float ax1 = fabsf(sx1), ay1 = fabsf(sy1);
            float d11 = fmaf(-T1_SLOPE, ax1, ay1);
            float d21 = fmaf(-T2_SLOPE, ax1, ay1);
            float e1 = SECT_EPS * (ax1 + ay1);
            int ndx1 = (d21 > 0.0f) ? 0 : ((sx1 > 0.0f) ? -1 : 1);
            int ndy1 = (d11 < 0.0f) ? 0 : ((sy1 > 0.0f) ? -1 : 1);
            bool nu1 = (fminf(fabsf(d11), fabsf(d21)) < e1)
                     || (fabsf(q1 - QE) <= QBAND_EPS * (q1 + QE));

            // ring write: row m -> slot (k-2)&3 (compile-time offset under unroll)
            const int sW = ((k - 2) & 3) * 128;
            *(float2*)(sb + sW + r0) = make_float2(Q0, Q1);

            // ---- NMS for row n = m-1 (rows m-2,m-1,m resident in ring) ----
            if (k >= 4) {
                const int n = m - 1;            // = Y0 + k - 4
                const int cen0 = ((sW + 384) & 511) + rb;   // row n, col rb
                float mp0 = sb[(cen0 + offP0) & 511];
                float mn0 = sb[(cen0 + offN0) & 511];
                float mp1 = sb[(cen0 + 1 + offP1) & 511];
                float mn1 = sb[(cen0 + 1 + offN1) & 511];
                float r0v = (mq0 > mp0 && mq0 > mn0 && mq0 >= QE) ? 1.0f : 0.0f;
                float r1v = (mq1 > mp1 && mq1 > mn1 && mq1 >= QE) ? 1.0f : 0.0f;
                if (outok)
                    *(float2*)(out + (size_t)n * IMG_W + x0i) = make_float2(r0v, r1v);
                // defer knife-edge pixels to the exact path
                float tb0 = TIE_EPS * mq0, tb1 = TIE_EPS * mq1;
                bool tie0 = (fabsf(mq0 - mp0) <= tb0) || (fabsf(mq0 - mn0) <= tb0);
                bool tie1 = (fabsf(mq1 - mp1) <= tb1) || (fabsf(mq1 - mn1) <= tb1);
                bool cand0 = mq0 >= QE * (1.0f - 3.0f * QBAND_EPS);
                bool cand1 = mq1 >= QE * (1.0f - 3.0f * QBAND_EPS);
                bool f0 = outok && cand0 && (unc0 || tie0);
                bool f1 = outok && cand1 && (unc1 || tie1);
                if (f0) {
                    unsigned id = atomicAdd(&fixn[wv], 1u);
                    if (id < CAP) flist[id] = ((unsigned)n << 12) | (unsigned)x0i;
                }
                if (f1) {
                    unsigned id = atomicAdd(&fixn[wv], 1u);
                    if (id < CAP) flist[id] = ((unsigned)n << 12) | (unsigned)x1i;
                }
            }
            // lag update
            mq0 = Q0; mq1 = Q1;
            int o0 = ndy0 * 128 + ndx0, o1 = ndy1 * 128 + ndx1;
            offP0 = o0 + 512; offN0 = 512 - o0;
            offP1 = o1 + 512; offN1 = 512 - o1;
            unc0 = nu0; unc1 = nu1;
        }
    }

    // ---- in-wave fixup: exact reference numerics for deferred pixels ----
    __threadfence();                            // retire fast-path stores before overwrite
    unsigned nf = fixn[wv];
    if (nf > CAP) nf = CAP;
    for (unsigned i = lane; i < nf; i += 64) {
        unsigned pk = flist[i];
        int xx = (int)(pk & 4095u), yy = (int)(pk >> 12);
        float sx, sy;
        sobel_at(img, xx, yy, sx, sy);          // exact gray (/3.0f) + exact taps
        int idx = slow_sector(sx, sy);          // exact atan2 (+double rescue)
        int dxo = ((DXPACK >> (2 * idx)) & 3) - 1;
        int dyo = ((DYPACK >> (2 * idx)) & 3) - 1;
        float mc = mag_at(img, xx, yy);
        float mp = mag_at(img, xx + dxo, yy + dyo);
        float mn = mag_at(img, xx - dxo, yy - dyo);
        out[(size_t)yy * IMG_W + xx] =
            (fminf(mc - mp, mc - mn) > 0.0f && mc >= 0.2f) ? 1.0f : 0.0f;
    }
}

extern "C" void kernel_launch(void* const* d_in, const int* in_sizes, int n_in,
                              void* d_out, int out_size, void* d_ws, size_t ws_size,
                              hipStream_t stream) {
    const float* img = (const float*)d_in[0];
    float* out = (float*)d_out;
    canny_main<<<dim3(8, IMG_H / R), dim3(64, 4), 0, stream>>>(img, out);
}